// Round 1
// baseline (89.388 us; speedup 1.0000x reference)
//
#include <hip/hip_runtime.h>
#include <hip/hip_bf16.h>
#include <math.h>

#define KCOMP 1024
#define DDIM  6
#define BPTS  16384

#define SPLIT 8              // K-chunks per point (one per wave)
#define CPT   (KCOMP/SPLIT)  // 128 components per thread
#define PTS   64             // points per block (one per lane)
#define NCOEF 28             // 21 quad + 6 linear + 1 const

// ---------------------------------------------------------------------------
// Kernel 1: per-component precompute.
// coefs[k][0..20]  : quad coefs for z=(x_i x_j, i<=j):  -0.5*P_ii (diag), -P_ij (off)
// coefs[k][21..26] : linear coefs: (P @ mu)_i
// coefs[k][27]     : log w_k - 0.5*(D log 2pi + logdet) - 0.5 * mu^T P mu
// where P = Sigma^{-1}.
// ---------------------------------------------------------------------------
__global__ void gmm_precompute(const float* __restrict__ means,
                               const float* __restrict__ covs,
                               const float* __restrict__ weights,
                               float* __restrict__ coefs) {
    int k = blockIdx.x * blockDim.x + threadIdx.x;
    if (k >= KCOMP) return;

    float A[6][6];
    const float* C = covs + k * 36;
    #pragma unroll
    for (int i = 0; i < 6; i++)
        #pragma unroll
        for (int j = 0; j < 6; j++)
            A[i][j] = C[i * 6 + j];

    // Cholesky: A = L L^T (lower)
    float L[6][6];
    #pragma unroll
    for (int j = 0; j < 6; j++) {
        float d = A[j][j];
        #pragma unroll
        for (int t = 0; t < 6; t++) if (t < j) d -= L[j][t] * L[j][t];
        float ljj = sqrtf(d);
        L[j][j] = ljj;
        float inv = 1.0f / ljj;
        #pragma unroll
        for (int i = 0; i < 6; i++) {
            if (i > j) {
                float s = A[i][j];
                #pragma unroll
                for (int t = 0; t < 6; t++) if (t < j) s -= L[i][t] * L[j][t];
                L[i][j] = s * inv;
            }
        }
    }

    // Li = L^{-1} (lower triangular)
    float Li[6][6];
    #pragma unroll
    for (int j = 0; j < 6; j++) {
        Li[j][j] = 1.0f / L[j][j];
        #pragma unroll
        for (int i = 0; i < 6; i++) {
            if (i > j) {
                float s = 0.0f;
                #pragma unroll
                for (int t = 0; t < 6; t++) if (t >= j && t < i) s += L[i][t] * Li[t][j];
                Li[i][j] = -s / L[i][i];
            }
        }
    }

    // P = Li^T Li = Sigma^{-1} (symmetric)
    float P[6][6];
    #pragma unroll
    for (int i = 0; i < 6; i++) {
        #pragma unroll
        for (int j = 0; j < 6; j++) {
            if (j >= i) {
                float s = 0.0f;
                int lo = (i > j) ? i : j;
                #pragma unroll
                for (int t = 0; t < 6; t++) if (t >= lo) s += Li[t][i] * Li[t][j];
                P[i][j] = s;
                P[j][i] = s;
            }
        }
    }

    float logdet = 0.0f;
    #pragma unroll
    for (int i = 0; i < 6; i++) logdet += logf(L[i][i]);
    logdet *= 2.0f;

    const float* mu = means + k * 6;
    float m[6];
    #pragma unroll
    for (int i = 0; i < 6; i++) m[i] = mu[i];

    float b[6];
    float muPmu = 0.0f;
    #pragma unroll
    for (int i = 0; i < 6; i++) {
        float s = 0.0f;
        #pragma unroll
        for (int j = 0; j < 6; j++) s += P[i][j] * m[j];
        b[i] = s;
        muPmu += s * m[i];
    }

    const float LOG_2PI = 1.8378770664093453f;
    float c = logf(weights[k]) - 0.5f * (6.0f * LOG_2PI + logdet) - 0.5f * muPmu;

    float* cf = coefs + k * NCOEF;
    int t = 0;
    #pragma unroll
    for (int i = 0; i < 6; i++)
        #pragma unroll
        for (int j = 0; j < 6; j++)
            if (j >= i) cf[t++] = (i == j) ? -0.5f * P[i][j] : -P[i][j];
    #pragma unroll
    for (int i = 0; i < 6; i++) cf[t++] = b[i];
    cf[27] = c;
}

// ---------------------------------------------------------------------------
// Kernel 2: main. Block = 512 threads = 8 waves. Wave w handles K-chunk w
// (wave-uniform => component coefs become scalar s_loads). Lane l handles
// point blockIdx.x*64 + l. Online logsumexp per thread, LDS combine.
// ---------------------------------------------------------------------------
__global__ __launch_bounds__(512, 2) void gmm_main(const float* __restrict__ x,
                                                   const float* __restrict__ coefs,
                                                   float* __restrict__ out) {
    const int lane = threadIdx.x & 63;
    const int wave = __builtin_amdgcn_readfirstlane((int)(threadIdx.x >> 6)); // 0..7
    const int p = blockIdx.x * PTS + lane;

    // Build per-point feature vector z (27 entries; const handled separately)
    float xv[6];
    const float* xp = x + p * 6;
    #pragma unroll
    for (int i = 0; i < 6; i++) xv[i] = xp[i];

    float z[27];
    {
        int t = 0;
        #pragma unroll
        for (int i = 0; i < 6; i++)
            #pragma unroll
            for (int j = 0; j < 6; j++)
                if (j >= i) z[t++] = xv[i] * xv[j];
        #pragma unroll
        for (int i = 0; i < 6; i++) z[t++] = xv[i];
    }

    float m = -1e30f;
    float s = 0.0f;
    const float* cf = coefs + (size_t)wave * CPT * NCOEF;

    for (int j = 0; j < CPT; j++) {
        float v = cf[27];
        #pragma unroll
        for (int t = 0; t < 27; t++) v = fmaf(cf[t], z[t], v);
        cf += NCOEF;
        float vm = fmaxf(v, m);
        s = fmaf(s, __expf(m - vm), __expf(v - vm));
        m = vm;
    }

    __shared__ float sm[SPLIT][PTS];
    __shared__ float ss[SPLIT][PTS];
    sm[wave][lane] = m;
    ss[wave][lane] = s;
    __syncthreads();

    if (threadIdx.x < PTS) {
        float M = sm[0][lane];
        #pragma unroll
        for (int c = 1; c < SPLIT; c++) M = fmaxf(M, sm[c][lane]);
        float S = 0.0f;
        #pragma unroll
        for (int c = 0; c < SPLIT; c++) S += ss[c][lane] * __expf(sm[c][lane] - M);
        out[p] = M + __logf(S);
    }
}

extern "C" void kernel_launch(void* const* d_in, const int* in_sizes, int n_in,
                              void* d_out, int out_size, void* d_ws, size_t ws_size,
                              hipStream_t stream) {
    const float* x       = (const float*)d_in[0];  // [B, 6]
    const float* means   = (const float*)d_in[1];  // [K, 6]
    const float* covs    = (const float*)d_in[2];  // [K, 6, 6]
    const float* weights = (const float*)d_in[3];  // [K]
    float* out = (float*)d_out;                    // [B]
    float* coefs = (float*)d_ws;                   // [K, 28] = 114,688 B

    gmm_precompute<<<KCOMP / 256, 256, 0, stream>>>(means, covs, weights, coefs);
    gmm_main<<<BPTS / PTS, 512, 0, stream>>>(x, coefs, out);
}

// Round 2
// 80.916 us; speedup vs baseline: 1.1047x; 1.1047x over previous
//
#include <hip/hip_runtime.h>
#include <hip/hip_bf16.h>
#include <math.h>

#define KCOMP 1024
#define DDIM  6
#define BPTS  16384

#define SPLIT 16             // K-chunks per point group (one per wave)
#define CPT   (KCOMP/SPLIT)  // 64 components per thread
#define PTS   64             // points per block (one per lane)
#define NCOEF 28             // 21 quad + 6 linear + 1 const

// ---------------------------------------------------------------------------
// Kernel 1: per-component precompute, LOG2 DOMAIN.
// v2(x) = log2(w_k N(x; mu_k, Sigma_k)) = sum_t cf[t] z[t] + cf[27]
// where z = (x_i x_j (i<=j), x_i) and all coefs carry a log2(e) factor:
//   cf[0..20]  = log2e * (-0.5*P_ii diag / -P_ij offdiag)
//   cf[21..26] = log2e * (P mu)_i
//   cf[27]     = log2e * (log w - 0.5(D log2pi + logdet) - 0.5 mu^T P mu)
// P = Sigma^{-1}. Since Sigma >= 0.1 I, v2 <= ~2 (no overflow of exp2 sums);
// underflow of all 1024 terms would need best v < -87 nats — unreachable here.
// ---------------------------------------------------------------------------
__global__ void gmm_precompute(const float* __restrict__ means,
                               const float* __restrict__ covs,
                               const float* __restrict__ weights,
                               float* __restrict__ coefs) {
    int k = blockIdx.x * blockDim.x + threadIdx.x;
    if (k >= KCOMP) return;

    float A[6][6];
    const float* C = covs + k * 36;
    #pragma unroll
    for (int i = 0; i < 6; i++)
        #pragma unroll
        for (int j = 0; j < 6; j++)
            A[i][j] = C[i * 6 + j];

    // Cholesky: A = L L^T (lower)
    float L[6][6];
    #pragma unroll
    for (int j = 0; j < 6; j++) {
        float d = A[j][j];
        #pragma unroll
        for (int t = 0; t < 6; t++) if (t < j) d -= L[j][t] * L[j][t];
        float ljj = sqrtf(d);
        L[j][j] = ljj;
        float inv = 1.0f / ljj;
        #pragma unroll
        for (int i = 0; i < 6; i++) {
            if (i > j) {
                float s = A[i][j];
                #pragma unroll
                for (int t = 0; t < 6; t++) if (t < j) s -= L[i][t] * L[j][t];
                L[i][j] = s * inv;
            }
        }
    }

    // Li = L^{-1} (lower triangular)
    float Li[6][6];
    #pragma unroll
    for (int j = 0; j < 6; j++) {
        Li[j][j] = 1.0f / L[j][j];
        #pragma unroll
        for (int i = 0; i < 6; i++) {
            if (i > j) {
                float s = 0.0f;
                #pragma unroll
                for (int t = 0; t < 6; t++) if (t >= j && t < i) s += L[i][t] * Li[t][j];
                Li[i][j] = -s / L[i][i];
            }
        }
    }

    // P = Li^T Li = Sigma^{-1} (symmetric)
    float P[6][6];
    #pragma unroll
    for (int i = 0; i < 6; i++) {
        #pragma unroll
        for (int j = 0; j < 6; j++) {
            if (j >= i) {
                float s = 0.0f;
                int lo = (i > j) ? i : j;
                #pragma unroll
                for (int t = 0; t < 6; t++) if (t >= lo) s += Li[t][i] * Li[t][j];
                P[i][j] = s;
                P[j][i] = s;
            }
        }
    }

    float logdet = 0.0f;
    #pragma unroll
    for (int i = 0; i < 6; i++) logdet += logf(L[i][i]);
    logdet *= 2.0f;

    const float* mu = means + k * 6;
    float m[6];
    #pragma unroll
    for (int i = 0; i < 6; i++) m[i] = mu[i];

    float b[6];
    float muPmu = 0.0f;
    #pragma unroll
    for (int i = 0; i < 6; i++) {
        float s = 0.0f;
        #pragma unroll
        for (int j = 0; j < 6; j++) s += P[i][j] * m[j];
        b[i] = s;
        muPmu += s * m[i];
    }

    const float LOG_2PI = 1.8378770664093453f;
    const float LOG2E   = 1.4426950408889634f;
    float c = logf(weights[k]) - 0.5f * (6.0f * LOG_2PI + logdet) - 0.5f * muPmu;

    float* cf = coefs + k * NCOEF;
    int t = 0;
    #pragma unroll
    for (int i = 0; i < 6; i++)
        #pragma unroll
        for (int j = 0; j < 6; j++)
            if (j >= i) cf[t++] = LOG2E * ((i == j) ? -0.5f * P[i][j] : -P[i][j]);
    #pragma unroll
    for (int i = 0; i < 6; i++) cf[t++] = LOG2E * b[i];
    cf[27] = LOG2E * c;
}

// ---------------------------------------------------------------------------
// Kernel 2: main. Block = 1024 threads = 16 waves; wave w = K-chunk w
// (wave-uniform pointer -> scalar s_loads for coefs). Lane l = point
// blockIdx.x*64 + l. Fixed-scale sum of exp2(v2): no online max needed.
// 256 blocks x 16 waves = 4096 waves = 4 waves/SIMD.
// ---------------------------------------------------------------------------
__global__ __launch_bounds__(1024, 4) void gmm_main(const float* __restrict__ x,
                                                    const float* __restrict__ coefs,
                                                    float* __restrict__ out) {
    const int lane = threadIdx.x & 63;
    const int wave = __builtin_amdgcn_readfirstlane((int)(threadIdx.x >> 6)); // 0..15
    const int p = blockIdx.x * PTS + lane;

    float xv[6];
    const float* xp = x + p * 6;
    #pragma unroll
    for (int i = 0; i < 6; i++) xv[i] = xp[i];

    float z[27];
    {
        int t = 0;
        #pragma unroll
        for (int i = 0; i < 6; i++)
            #pragma unroll
            for (int j = 0; j < 6; j++)
                if (j >= i) z[t++] = xv[i] * xv[j];
        #pragma unroll
        for (int i = 0; i < 6; i++) z[t++] = xv[i];
    }

    float s0 = 0.0f, s1 = 0.0f;
    const float* cf = coefs + (size_t)wave * CPT * NCOEF;

    #pragma unroll 2
    for (int j = 0; j < CPT; j++) {
        // 3 parallel accumulator chains (9 FMAs each) to break the dep chain
        float v0 = cf[27];
        float v1 = 0.0f;
        float v2 = 0.0f;
        #pragma unroll
        for (int t = 0; t < 9; t++)  v0 = fmaf(cf[t],      z[t],      v0);
        #pragma unroll
        for (int t = 0; t < 9; t++)  v1 = fmaf(cf[t + 9],  z[t + 9],  v1);
        #pragma unroll
        for (int t = 0; t < 9; t++)  v2 = fmaf(cf[t + 18], z[t + 18], v2);
        cf += NCOEF;
        float v = (v0 + v1) + v2;
        float e = __builtin_amdgcn_exp2f(v);   // raw v_exp_f32
        if (j & 1) s1 += e; else s0 += e;
    }

    __shared__ float ss[SPLIT][PTS];
    ss[wave][lane] = s0 + s1;
    __syncthreads();

    if (threadIdx.x < PTS) {
        float S = 0.0f;
        #pragma unroll
        for (int c = 0; c < SPLIT; c++) S += ss[c][lane];
        const float LN2 = 0.6931471805599453f;
        out[p] = LN2 * __builtin_amdgcn_logf(S);  // raw v_log_f32 (log2)
    }
}

extern "C" void kernel_launch(void* const* d_in, const int* in_sizes, int n_in,
                              void* d_out, int out_size, void* d_ws, size_t ws_size,
                              hipStream_t stream) {
    const float* x       = (const float*)d_in[0];  // [B, 6]
    const float* means   = (const float*)d_in[1];  // [K, 6]
    const float* covs    = (const float*)d_in[2];  // [K, 6, 6]
    const float* weights = (const float*)d_in[3];  // [K]
    float* out = (float*)d_out;                    // [B]
    float* coefs = (float*)d_ws;                   // [K, 28] = 114,688 B

    gmm_precompute<<<KCOMP / 256, 256, 0, stream>>>(means, covs, weights, coefs);
    gmm_main<<<BPTS / PTS, 1024, 0, stream>>>(x, coefs, out);
}